// Round 3
// baseline (159.260 us; speedup 1.0000x reference)
//
#include <hip/hip_runtime.h>

#define BATCH 1024
#define NANCH 3125
#define LAMB  5.0f
#define SPLIT 4
#define CHUNK ((NANCH + SPLIT - 1) / SPLIT)   // 782
#define NBLK  (BATCH * SPLIT)                 // 4096

__device__ __forceinline__ float wave_red_f(float v) {
    #pragma unroll
    for (int o = 32; o > 0; o >>= 1) v += __shfl_down(v, o, 64);
    return v;
}

// grid = NBLK, block = 256. Each block reduces a chunk of one batch row into 5
// partial sums stored SoA: part[k*NBLK + blk], k in {ce_pos, ce_neg, sl, pos, neg}.
// The last block to finish combines all partials and writes the 3 outputs.
__global__ __launch_bounds__(256) void fused_kernel(
    const float* __restrict__ c_pred,    // [B,N,2]
    const float* __restrict__ r_pred,    // [B,N,4]
    const float* __restrict__ r_target,  // [B,N,4]
    const int*   __restrict__ label,     // [B,N]
    float*       __restrict__ part,      // [5, NBLK]
    unsigned*    __restrict__ counter,   // [1], zeroed per launch
    float*       __restrict__ out)       // [3]
{
    const int blk = blockIdx.x;
    const int b   = blk / SPLIT;
    const int s   = blk % SPLIT;
    const int tid = threadIdx.x;

    const float2* c2 = (const float2*)(c_pred   + (size_t)b * NANCH * 2);
    const float4* rp = (const float4*)(r_pred   + (size_t)b * NANCH * 4);
    const float4* rt = (const float4*)(r_target + (size_t)b * NANCH * 4);
    const int*    lb = label + (size_t)b * NANCH;

    const int end = min((s + 1) * CHUNK, NANCH);

    float cp = 0.f, cn = 0.f, sl = 0.f, pc = 0.f, nc = 0.f;

    for (int i = s * CHUNK + tid; i < end; i += 256) {
        const int    l = lb[i];
        const float2 c = c2[i];
        const float4 p = rp[i];
        const float4 t = rt[i];

        const float isp = (l == 1) ? 1.f : 0.f;
        const float isn = (l == 0) ? 1.f : 0.f;

        const float m   = fmaxf(c.x, c.y);
        const float lse = m + log1pf(__expf(-fabsf(c.x - c.y)));

        pc += isp;
        nc += isn;
        cp += isp * (lse - c.y);   // -logp[...,1]
        cn += isn * (lse - c.x);   // -logp[...,0]

        float s4 = 0.f, d, a;
        d = p.x - t.x; a = fabsf(d); s4 += (a < 1.f) ? 0.5f * d * d : a - 0.5f;
        d = p.y - t.y; a = fabsf(d); s4 += (a < 1.f) ? 0.5f * d * d : a - 0.5f;
        d = p.z - t.z; a = fabsf(d); s4 += (a < 1.f) ? 0.5f * d * d : a - 0.5f;
        d = p.w - t.w; a = fabsf(d); s4 += (a < 1.f) ? 0.5f * d * d : a - 0.5f;
        sl += isp * s4 * 0.25f;
    }

    cp = wave_red_f(cp);
    cn = wave_red_f(cn);
    sl = wave_red_f(sl);
    pc = wave_red_f(pc);
    nc = wave_red_f(nc);

    __shared__ float sm[5][4];
    const int wid = tid >> 6, lane = tid & 63;
    if (lane == 0) {
        sm[0][wid] = cp; sm[1][wid] = cn; sm[2][wid] = sl;
        sm[3][wid] = pc; sm[4][wid] = nc;
    }
    __syncthreads();

    __shared__ unsigned s_last;
    if (tid == 0) {
        part[0 * NBLK + blk] = sm[0][0] + sm[0][1] + sm[0][2] + sm[0][3];
        part[1 * NBLK + blk] = sm[1][0] + sm[1][1] + sm[1][2] + sm[1][3];
        part[2 * NBLK + blk] = sm[2][0] + sm[2][1] + sm[2][2] + sm[2][3];
        part[3 * NBLK + blk] = sm[3][0] + sm[3][1] + sm[3][2] + sm[3][3];
        part[4 * NBLK + blk] = sm[4][0] + sm[4][1] + sm[4][2] + sm[4][3];
        __threadfence();   // make partials visible device-wide before the ticket
        const unsigned old = atomicAdd(counter, 1u);
        s_last = (old == NBLK - 1) ? 1u : 0u;
    }
    __syncthreads();

    if (s_last) {
        __threadfence();   // acquire side
        float csum = 0.f, rsum = 0.f;
        for (int bb = tid; bb < BATCH; bb += 256) {
            float vcp = 0.f, vcn = 0.f, vsl = 0.f, vpc = 0.f, vnc = 0.f;
            #pragma unroll
            for (int ss = 0; ss < SPLIT; ++ss) {
                const int idx = bb * SPLIT + ss;
                vcp += __hip_atomic_load(&part[0 * NBLK + idx], __ATOMIC_RELAXED, __HIP_MEMORY_SCOPE_AGENT);
                vcn += __hip_atomic_load(&part[1 * NBLK + idx], __ATOMIC_RELAXED, __HIP_MEMORY_SCOPE_AGENT);
                vsl += __hip_atomic_load(&part[2 * NBLK + idx], __ATOMIC_RELAXED, __HIP_MEMORY_SCOPE_AGENT);
                vpc += __hip_atomic_load(&part[3 * NBLK + idx], __ATOMIC_RELAXED, __HIP_MEMORY_SCOPE_AGENT);
                vnc += __hip_atomic_load(&part[4 * NBLK + idx], __ATOMIC_RELAXED, __HIP_MEMORY_SCOPE_AGENT);
            }
            const bool haspos = (vpc > 0.5f);
            const float pos_mean = haspos ? vcp / fmaxf(vpc, 1.f) : 0.f;
            const float neg_mean = vcn / fmaxf(vnc, 1.f);
            csum += (pos_mean + neg_mean) * 0.5f;
            rsum += haspos ? vsl / fmaxf(vpc, 1.f) : 0.f;
        }

        csum = wave_red_f(csum);
        rsum = wave_red_f(rsum);

        __shared__ float s_c[4], s_r[4];
        if (lane == 0) { s_c[wid] = csum; s_r[wid] = rsum; }
        __syncthreads();
        if (tid == 0) {
            float cs = 0.f, rs = 0.f;
            #pragma unroll
            for (int w = 0; w < 4; ++w) { cs += s_c[w]; rs += s_r[w]; }
            const float c_loss = cs / (float)BATCH;
            const float r_loss = rs / (float)BATCH;
            out[0] = c_loss;
            out[1] = r_loss;
            out[2] = c_loss + LAMB * r_loss;
        }
    }
}

extern "C" void kernel_launch(void* const* d_in, const int* in_sizes, int n_in,
                              void* d_out, int out_size, void* d_ws, size_t ws_size,
                              hipStream_t stream) {
    const float* c_pred   = (const float*)d_in[0];
    const float* r_pred   = (const float*)d_in[1];
    const float* r_target = (const float*)d_in[2];
    const int*   label    = (const int*)d_in[3];
    float*       out      = (float*)d_out;

    unsigned* counter = (unsigned*)d_ws;                 // 4 B, zeroed per launch
    float*    part    = (float*)((char*)d_ws + 256);     // 5*NBLK floats = 80 KiB

    hipMemsetAsync(counter, 0, sizeof(unsigned), stream);
    fused_kernel<<<NBLK, 256, 0, stream>>>(c_pred, r_pred, r_target, label,
                                           part, counter, out);
}

// Round 4
// 62.123 us; speedup vs baseline: 2.5636x; 2.5636x over previous
//
#include <hip/hip_runtime.h>

#define BATCH 1024
#define NANCH 3125
#define LAMB  5.0f
#define INV_B (1.0f / 1024.0f)

__device__ __forceinline__ float wave_red_f(float v) {
    #pragma unroll
    for (int o = 32; o > 0; o >>= 1) v += __shfl_down(v, o, 64);
    return v;
}

// grid = BATCH, block = 256. One block per batch row: full row sums -> local
// per-batch contributions -> relaxed device-scope atomicAdd into accumulators.
// Last block (acq_rel ticket) writes the 3 outputs. NO threadfence (R3 lesson:
// per-block device fences force L2 writebacks and serialize the machine).
__global__ __launch_bounds__(256) void fused_kernel(
    const float* __restrict__ c_pred,    // [B,N,2]
    const float* __restrict__ r_pred,    // [B,N,4]
    const float* __restrict__ r_target,  // [B,N,4]
    const int*   __restrict__ label,     // [B,N]
    float*       __restrict__ c_acc,     // [1] zeroed per launch
    float*       __restrict__ r_acc,     // [1] zeroed per launch (different line)
    unsigned*    __restrict__ counter,   // [1] zeroed per launch (different line)
    float*       __restrict__ out)       // [3]
{
    const int b   = blockIdx.x;
    const int tid = threadIdx.x;

    const float2* c2 = (const float2*)(c_pred   + (size_t)b * NANCH * 2);
    const float4* rp = (const float4*)(r_pred   + (size_t)b * NANCH * 4);
    const float4* rt = (const float4*)(r_target + (size_t)b * NANCH * 4);
    const int*    lb = label + (size_t)b * NANCH;

    float cp = 0.f, cn = 0.f, sl = 0.f, pc = 0.f, nc = 0.f;

    #pragma unroll 2
    for (int i = tid; i < NANCH; i += 256) {
        const int    l = lb[i];
        const float2 c = c2[i];
        const float4 p = rp[i];
        const float4 t = rt[i];

        const float isp = (l == 1) ? 1.f : 0.f;
        const float isn = (l == 0) ? 1.f : 0.f;

        // log-sum-exp over 2 logits (fast path: v_exp + v_log)
        const float m   = fmaxf(c.x, c.y);
        const float lse = m + __logf(1.f + __expf(-fabsf(c.x - c.y)));

        pc += isp;
        nc += isn;
        cp += isp * (lse - c.y);   // -logp[...,1]
        cn += isn * (lse - c.x);   // -logp[...,0]

        float s4 = 0.f, d, a;
        d = p.x - t.x; a = fabsf(d); s4 += (a < 1.f) ? 0.5f * d * d : a - 0.5f;
        d = p.y - t.y; a = fabsf(d); s4 += (a < 1.f) ? 0.5f * d * d : a - 0.5f;
        d = p.z - t.z; a = fabsf(d); s4 += (a < 1.f) ? 0.5f * d * d : a - 0.5f;
        d = p.w - t.w; a = fabsf(d); s4 += (a < 1.f) ? 0.5f * d * d : a - 0.5f;
        sl += isp * s4 * 0.25f;
    }

    cp = wave_red_f(cp);
    cn = wave_red_f(cn);
    sl = wave_red_f(sl);
    pc = wave_red_f(pc);
    nc = wave_red_f(nc);

    __shared__ float sm[5][4];
    const int wid = tid >> 6, lane = tid & 63;
    if (lane == 0) {
        sm[0][wid] = cp; sm[1][wid] = cn; sm[2][wid] = sl;
        sm[3][wid] = pc; sm[4][wid] = nc;
    }
    __syncthreads();

    if (tid == 0) {
        const float tcp = sm[0][0] + sm[0][1] + sm[0][2] + sm[0][3];
        const float tcn = sm[1][0] + sm[1][1] + sm[1][2] + sm[1][3];
        const float tsl = sm[2][0] + sm[2][1] + sm[2][2] + sm[2][3];
        const float tpc = sm[3][0] + sm[3][1] + sm[3][2] + sm[3][3];
        const float tnc = sm[4][0] + sm[4][1] + sm[4][2] + sm[4][3];

        const bool  haspos   = (tpc > 0.5f);
        const float pos_mean = haspos ? tcp / tpc : 0.f;
        const float neg_mean = tcn / fmaxf(tnc, 1.f);
        const float c_contrib = (pos_mean + neg_mean) * 0.5f * INV_B;
        const float r_contrib = (haspos ? tsl / tpc : 0.f) * INV_B;

        // device-scope atomics only — coherent point, no cache-flush fence
        __hip_atomic_fetch_add(c_acc, c_contrib, __ATOMIC_RELAXED, __HIP_MEMORY_SCOPE_AGENT);
        __hip_atomic_fetch_add(r_acc, r_contrib, __ATOMIC_RELAXED, __HIP_MEMORY_SCOPE_AGENT);
        const unsigned old = __hip_atomic_fetch_add(counter, 1u, __ATOMIC_ACQ_REL, __HIP_MEMORY_SCOPE_AGENT);
        if (old == BATCH - 1) {
            const float c_loss = __hip_atomic_load(c_acc, __ATOMIC_ACQUIRE, __HIP_MEMORY_SCOPE_AGENT);
            const float r_loss = __hip_atomic_load(r_acc, __ATOMIC_ACQUIRE, __HIP_MEMORY_SCOPE_AGENT);
            out[0] = c_loss;
            out[1] = r_loss;
            out[2] = c_loss + LAMB * r_loss;
        }
    }
}

extern "C" void kernel_launch(void* const* d_in, const int* in_sizes, int n_in,
                              void* d_out, int out_size, void* d_ws, size_t ws_size,
                              hipStream_t stream) {
    const float* c_pred   = (const float*)d_in[0];
    const float* r_pred   = (const float*)d_in[1];
    const float* r_target = (const float*)d_in[2];
    const int*   label    = (const int*)d_in[3];
    float*       out      = (float*)d_out;

    float*    c_acc   = (float*)d_ws;                      // offset 0
    float*    r_acc   = (float*)((char*)d_ws + 256);       // separate cacheline
    unsigned* counter = (unsigned*)((char*)d_ws + 512);    // separate cacheline

    hipMemsetAsync(d_ws, 0, 768, stream);
    fused_kernel<<<BATCH, 256, 0, stream>>>(c_pred, r_pred, r_target, label,
                                            c_acc, r_acc, counter, out);
}

// Round 5
// 29.746 us; speedup vs baseline: 5.3540x; 2.0885x over previous
//
#include <hip/hip_runtime.h>

#define BATCH 1024
#define NANCH 3125
#define LAMB  5.0f
#define SPLIT 4
#define CHUNK ((NANCH + SPLIT - 1) / SPLIT)   // 782
#define NBLK  (BATCH * SPLIT)                 // 4096

__device__ __forceinline__ float wave_red_f(float v) {
    #pragma unroll
    for (int o = 32; o > 0; o >>= 1) v += __shfl_down(v, o, 64);
    return v;
}

// grid = NBLK, block = 256. Each block reduces a chunk of one batch row into 5
// partials stored AoS per block: partial[blk*5 + k]. Conditional r loads: only
// positive anchors touch r_pred/r_target (saves ~2/3 of r bytes AND ~1/3 of
// VMEM instruction issue — R1 vs R4 showed this wins at any occupancy).
__global__ __launch_bounds__(256) void partial_kernel(
    const float* __restrict__ c_pred,    // [B,N,2]
    const float* __restrict__ r_pred,    // [B,N,4]
    const float* __restrict__ r_target,  // [B,N,4]
    const int*   __restrict__ label,     // [B,N]
    float*       __restrict__ partial)   // [NBLK, 5]
{
    const int blk = blockIdx.x;
    const int b   = blk / SPLIT;
    const int s   = blk % SPLIT;
    const int tid = threadIdx.x;

    const float2* c2 = (const float2*)(c_pred   + (size_t)b * NANCH * 2);
    const float4* rp = (const float4*)(r_pred   + (size_t)b * NANCH * 4);
    const float4* rt = (const float4*)(r_target + (size_t)b * NANCH * 4);
    const int*    lb = label + (size_t)b * NANCH;

    const int end = min((s + 1) * CHUNK, NANCH);

    float cp = 0.f, cn = 0.f, sl = 0.f, pc = 0.f, nc = 0.f;

    for (int i = s * CHUNK + tid; i < end; i += 256) {
        const int    l = lb[i];
        const float2 c = c2[i];

        const float m   = fmaxf(c.x, c.y);
        const float lse = m + __logf(1.f + __expf(-fabsf(c.x - c.y)));

        if (l == 1) {
            pc += 1.f;
            cp += lse - c.y;                 // -logp[...,1]
            const float4 p = rp[i];
            const float4 t = rt[i];
            float s4 = 0.f, d, a;
            d = p.x - t.x; a = fabsf(d); s4 += (a < 1.f) ? 0.5f * d * d : a - 0.5f;
            d = p.y - t.y; a = fabsf(d); s4 += (a < 1.f) ? 0.5f * d * d : a - 0.5f;
            d = p.z - t.z; a = fabsf(d); s4 += (a < 1.f) ? 0.5f * d * d : a - 0.5f;
            d = p.w - t.w; a = fabsf(d); s4 += (a < 1.f) ? 0.5f * d * d : a - 0.5f;
            sl += s4 * 0.25f;
        } else if (l == 0) {
            nc += 1.f;
            cn += lse - c.x;                 // -logp[...,0]
        }
    }

    cp = wave_red_f(cp);
    cn = wave_red_f(cn);
    sl = wave_red_f(sl);
    pc = wave_red_f(pc);
    nc = wave_red_f(nc);

    __shared__ float sm[5][4];
    const int wid = tid >> 6, lane = tid & 63;
    if (lane == 0) {
        sm[0][wid] = cp; sm[1][wid] = cn; sm[2][wid] = sl;
        sm[3][wid] = pc; sm[4][wid] = nc;
    }
    __syncthreads();
    if (tid < 5) {   // 5 threads each write one stat — single pass, no serial loop
        const int k = tid;
        partial[(size_t)blk * 5 + k] = sm[k][0] + sm[k][1] + sm[k][2] + sm[k][3];
    }
}

// grid = 1, block = 512. Combine SPLIT partials per batch, per-batch epilogue,
// reduce over batches, emit (c_loss, r_loss, t_loss).
__global__ __launch_bounds__(512) void finalize_kernel(
    const float* __restrict__ partial,   // [NBLK, 5]
    float*       __restrict__ out)       // [3]
{
    const int tid = threadIdx.x;
    float csum = 0.f, rsum = 0.f;

    for (int b = tid; b < BATCH; b += 512) {
        float cp = 0.f, cn = 0.f, sl = 0.f, pc = 0.f, nc = 0.f;
        #pragma unroll
        for (int s = 0; s < SPLIT; ++s) {
            const float* p = partial + ((size_t)b * SPLIT + s) * 5;
            cp += p[0]; cn += p[1]; sl += p[2]; pc += p[3]; nc += p[4];
        }
        const bool haspos = (pc > 0.5f);
        const float pos_mean = haspos ? cp / pc : 0.f;
        const float neg_mean = cn / fmaxf(nc, 1.f);
        csum += (pos_mean + neg_mean) * 0.5f;
        rsum += haspos ? sl / pc : 0.f;
    }

    csum = wave_red_f(csum);
    rsum = wave_red_f(rsum);

    __shared__ float s_c[8], s_r[8];
    const int wid = tid >> 6, lane = tid & 63;
    if (lane == 0) { s_c[wid] = csum; s_r[wid] = rsum; }
    __syncthreads();
    if (tid == 0) {
        float cs = 0.f, rs = 0.f;
        #pragma unroll
        for (int w = 0; w < 8; ++w) { cs += s_c[w]; rs += s_r[w]; }
        const float c_loss = cs / (float)BATCH;
        const float r_loss = rs / (float)BATCH;
        out[0] = c_loss;
        out[1] = r_loss;
        out[2] = c_loss + LAMB * r_loss;
    }
}

extern "C" void kernel_launch(void* const* d_in, const int* in_sizes, int n_in,
                              void* d_out, int out_size, void* d_ws, size_t ws_size,
                              hipStream_t stream) {
    const float* c_pred   = (const float*)d_in[0];
    const float* r_pred   = (const float*)d_in[1];
    const float* r_target = (const float*)d_in[2];
    const int*   label    = (const int*)d_in[3];
    float*       out      = (float*)d_out;
    float*       partial  = (float*)d_ws;   // NBLK*5 floats = 80 KiB

    partial_kernel<<<NBLK, 256, 0, stream>>>(c_pred, r_pred, r_target, label, partial);
    finalize_kernel<<<1, 512, 0, stream>>>(partial, out);
}

// Round 6
// 28.622 us; speedup vs baseline: 5.5643x; 1.0393x over previous
//
#include <hip/hip_runtime.h>

#define BATCH 1024
#define NANCH 3125
#define LAMB  5.0f
#define SPLIT 4
#define CHUNK ((NANCH + SPLIT - 1) / SPLIT)   // 782 (last chunk 779)
#define NBLK  (BATCH * SPLIT)                 // 4096

__device__ __forceinline__ float wave_red_f(float v) {
    #pragma unroll
    for (int o = 32; o > 0; o >>= 1) v += __shfl_down(v, o, 64);
    return v;
}

__device__ __forceinline__ float lse2(float2 c) {
    const float m = fmaxf(c.x, c.y);
    return m + __logf(1.f + __expf(-fabsf(c.x - c.y)));
}

__device__ __forceinline__ float sl1(float4 p, float4 t) {
    float s4 = 0.f, d, a;
    d = p.x - t.x; a = fabsf(d); s4 += (a < 1.f) ? 0.5f * d * d : a - 0.5f;
    d = p.y - t.y; a = fabsf(d); s4 += (a < 1.f) ? 0.5f * d * d : a - 0.5f;
    d = p.z - t.z; a = fabsf(d); s4 += (a < 1.f) ? 0.5f * d * d : a - 0.5f;
    d = p.w - t.w; a = fabsf(d); s4 += (a < 1.f) ? 0.5f * d * d : a - 0.5f;
    return s4 * 0.25f;
}

// grid = NBLK, block = 256. Unrolled x4 with issue/consume phases:
// phase 1: all 4 label + 4 c loads issued (independent, overlap in flight);
// phase 2: 4 branch blocks that ONLY issue conditional r loads (conditions all
//          ready together -> loads from all 4 slots overlap);
// phase 3: consume. Keeps R5's byte savings, restores R2's MLP.
__global__ __launch_bounds__(256) void partial_kernel(
    const float* __restrict__ c_pred,    // [B,N,2]
    const float* __restrict__ r_pred,    // [B,N,4]
    const float* __restrict__ r_target,  // [B,N,4]
    const int*   __restrict__ label,     // [B,N]
    float*       __restrict__ partial)   // [NBLK, 5]
{
    const int blk = blockIdx.x;
    const int b   = blk / SPLIT;
    const int s   = blk % SPLIT;
    const int tid = threadIdx.x;

    const float2* c2 = (const float2*)(c_pred   + (size_t)b * NANCH * 2);
    const float4* rp = (const float4*)(r_pred   + (size_t)b * NANCH * 4);
    const float4* rt = (const float4*)(r_target + (size_t)b * NANCH * 4);
    const int*    lb = label + (size_t)b * NANCH;

    const int start = s * CHUNK;
    const int end   = min(start + CHUNK, NANCH);

    // slots: i0..i2 always in range (min chunk 779 > 767); slot 3 masked
    const int  i0 = start + tid;
    const int  i1 = i0 + 256;
    const int  i2 = i0 + 512;
    const int  i3 = i0 + 768;
    const bool v3 = (i3 < end);
    const int  j3 = v3 ? i3 : i0;

    // ---- phase 1: independent label + c loads, all in flight together ----
    const int l0 = lb[i0];
    const int l1 = lb[i1];
    const int l2 = lb[i2];
    int       l3 = lb[j3];
    const float2 c0 = c2[i0];
    const float2 c1 = c2[i1];
    const float2 cc2 = c2[i2];
    const float2 c3 = c2[j3];
    if (!v3) l3 = -1;   // OOB slot contributes nothing

    // ---- phase 2: issue-only conditional r loads (back-to-back branches) ----
    const bool p0 = (l0 == 1), p1 = (l1 == 1), p2 = (l2 == 1), p3 = (l3 == 1);
    float4 P0, T0, P1, T1, P2, T2, P3, T3;
    if (p0) { P0 = rp[i0]; T0 = rt[i0]; }
    if (p1) { P1 = rp[i1]; T1 = rt[i1]; }
    if (p2) { P2 = rp[i2]; T2 = rt[i2]; }
    if (p3) { P3 = rp[i3]; T3 = rt[i3]; }

    // ---- phase 3: consume ----
    float cp = 0.f, cn = 0.f, sl = 0.f, pc = 0.f, nc = 0.f;

    const float e0 = lse2(c0), e1 = lse2(c1), e2 = lse2(cc2), e3 = lse2(c3);
    const bool n0 = (l0 == 0), n1 = (l1 == 0), n2 = (l2 == 0), n3 = (l3 == 0);

    pc = (p0 ? 1.f : 0.f) + (p1 ? 1.f : 0.f) + (p2 ? 1.f : 0.f) + (p3 ? 1.f : 0.f);
    nc = (n0 ? 1.f : 0.f) + (n1 ? 1.f : 0.f) + (n2 ? 1.f : 0.f) + (n3 ? 1.f : 0.f);
    cp = (p0 ? (e0 - c0.y) : 0.f) + (p1 ? (e1 - c1.y) : 0.f)
       + (p2 ? (e2 - cc2.y) : 0.f) + (p3 ? (e3 - c3.y) : 0.f);
    cn = (n0 ? (e0 - c0.x) : 0.f) + (n1 ? (e1 - c1.x) : 0.f)
       + (n2 ? (e2 - cc2.x) : 0.f) + (n3 ? (e3 - c3.x) : 0.f);

    if (p0) sl += sl1(P0, T0);
    if (p1) sl += sl1(P1, T1);
    if (p2) sl += sl1(P2, T2);
    if (p3) sl += sl1(P3, T3);

    // ---- block reduction ----
    cp = wave_red_f(cp);
    cn = wave_red_f(cn);
    sl = wave_red_f(sl);
    pc = wave_red_f(pc);
    nc = wave_red_f(nc);

    __shared__ float sm[5][4];
    const int wid = tid >> 6, lane = tid & 63;
    if (lane == 0) {
        sm[0][wid] = cp; sm[1][wid] = cn; sm[2][wid] = sl;
        sm[3][wid] = pc; sm[4][wid] = nc;
    }
    __syncthreads();
    if (tid < 5) {
        const int k = tid;
        partial[(size_t)blk * 5 + k] = sm[k][0] + sm[k][1] + sm[k][2] + sm[k][3];
    }
}

// grid = 1, block = 512.
__global__ __launch_bounds__(512) void finalize_kernel(
    const float* __restrict__ partial,   // [NBLK, 5]
    float*       __restrict__ out)       // [3]
{
    const int tid = threadIdx.x;
    float csum = 0.f, rsum = 0.f;

    for (int b = tid; b < BATCH; b += 512) {
        float cp = 0.f, cn = 0.f, sl = 0.f, pc = 0.f, nc = 0.f;
        #pragma unroll
        for (int s = 0; s < SPLIT; ++s) {
            const float* p = partial + ((size_t)b * SPLIT + s) * 5;
            cp += p[0]; cn += p[1]; sl += p[2]; pc += p[3]; nc += p[4];
        }
        const bool haspos = (pc > 0.5f);
        const float pos_mean = haspos ? cp / pc : 0.f;
        const float neg_mean = cn / fmaxf(nc, 1.f);
        csum += (pos_mean + neg_mean) * 0.5f;
        rsum += haspos ? sl / pc : 0.f;
    }

    csum = wave_red_f(csum);
    rsum = wave_red_f(rsum);

    __shared__ float s_c[8], s_r[8];
    const int wid = tid >> 6, lane = tid & 63;
    if (lane == 0) { s_c[wid] = csum; s_r[wid] = rsum; }
    __syncthreads();
    if (tid == 0) {
        float cs = 0.f, rs = 0.f;
        #pragma unroll
        for (int w = 0; w < 8; ++w) { cs += s_c[w]; rs += s_r[w]; }
        const float c_loss = cs / (float)BATCH;
        const float r_loss = rs / (float)BATCH;
        out[0] = c_loss;
        out[1] = r_loss;
        out[2] = c_loss + LAMB * r_loss;
    }
}

extern "C" void kernel_launch(void* const* d_in, const int* in_sizes, int n_in,
                              void* d_out, int out_size, void* d_ws, size_t ws_size,
                              hipStream_t stream) {
    const float* c_pred   = (const float*)d_in[0];
    const float* r_pred   = (const float*)d_in[1];
    const float* r_target = (const float*)d_in[2];
    const int*   label    = (const int*)d_in[3];
    float*       out      = (float*)d_out;
    float*       partial  = (float*)d_ws;   // NBLK*5 floats = 80 KiB

    partial_kernel<<<NBLK, 256, 0, stream>>>(c_pred, r_pred, r_target, label, partial);
    finalize_kernel<<<1, 512, 0, stream>>>(partial, out);
}